// Round 1
// baseline (79.603 us; speedup 1.0000x reference)
//
#include <hip/hip_runtime.h>

#define N    384
#define DIM  256
#define MARGIN_F 0.2f

// ---------------------------------------------------------------------------
// Workspace layout (floats unless noted):
//   eT    : [0, DIM*N)               normalized embeddings, TRANSPOSED (k-major)
//   sq    : [DIM*N, DIM*N + N)       per-row sum(e_norm^2)  (~1.0 each)
//   D     : next N*N                 pairwise distance matrix
//   accum : next: 1 float (sum), 1 uint (count)
// Total ≈ 985 KB.
// ---------------------------------------------------------------------------

__global__ __launch_bounds__(DIM) void normalize_kernel(
    const float* __restrict__ emb, float* __restrict__ eT,
    float* __restrict__ sq, float* __restrict__ accum_sum,
    unsigned int* __restrict__ accum_cnt)
{
    const int row = blockIdx.x;    // 0..N-1
    const int tid = threadIdx.x;   // 0..DIM-1, one element per thread

    float v = emb[row * DIM + tid];
    float s = v * v;
    // wave(64) shuffle reduce
    #pragma unroll
    for (int off = 32; off > 0; off >>= 1) s += __shfl_down(s, off, 64);
    __shared__ float wsum[4];
    const int wave = tid >> 6, lane = tid & 63;
    if (lane == 0) wsum[wave] = s;
    __syncthreads();
    if (tid == 0) wsum[0] = wsum[0] + wsum[1] + wsum[2] + wsum[3];
    __syncthreads();
    const float tot = wsum[0];

    const float inv = 1.0f / fmaxf(sqrtf(tot), 1e-12f);
    const float vn  = v * inv;
    eT[tid * N + row] = vn;           // transposed store for coalesced dist reads

    if (tid == 0) {
        sq[row] = tot * inv * inv;    // sum(e_norm^2), matches ref's recompute to ~1e-7
        if (row == 0) { accum_sum[0] = 0.0f; accum_cnt[0] = 0u; }
    }
}

__global__ __launch_bounds__(N) void dist_kernel(
    const float* __restrict__ eT, const float* __restrict__ sq,
    float* __restrict__ D)
{
    const int i = blockIdx.x;      // anchor row
    const int j = threadIdx.x;     // 0..N-1, one column per thread

    __shared__ float ei[DIM];
    if (j < DIM) ei[j] = eT[j * N + i];   // gather anchor row (L2-hot)
    __syncthreads();

    float acc = 0.0f;
    #pragma unroll 8
    for (int k = 0; k < DIM; ++k)
        acc += ei[k] * eT[k * N + j];     // ei: LDS broadcast; eT: coalesced over j

    const float d2 = fmaxf(sq[i] + sq[j] - 2.0f * acc, 0.0f);
    D[i * N + j] = (d2 > 0.0f) ? sqrtf(d2) : 0.0f;   // ref: sqrt(where(pos,d2,1))*pos
}

__global__ __launch_bounds__(256) void triplet_kernel(
    const float* __restrict__ D, const int* __restrict__ labels,
    float* __restrict__ accum_sum, unsigned int* __restrict__ accum_cnt)
{
    const int i   = blockIdx.x;    // anchor
    const int tid = threadIdx.x;   // 256 threads

    __shared__ float Drow[N];
    __shared__ int   lab[N];
    __shared__ int   posList[N];
    __shared__ int   nPos;
    if (tid == 0) nPos = 0;
    __syncthreads();

    for (int j = tid; j < N; j += 256) {
        Drow[j] = D[i * N + j];
        lab[j]  = labels[j];
    }
    __syncthreads();

    const int li = lab[i];
    for (int j = tid; j < N; j += 256) {
        if (lab[j] == li && j != i) {
            int idx = atomicAdd(&nPos, 1);
            posList[idx] = j;
        }
    }
    __syncthreads();

    float        lsum = 0.0f;
    unsigned int lcnt = 0u;
    const int np = nPos;                    // ~11 positives per anchor
    for (int p = 0; p < np; ++p) {
        const float dj = Drow[posList[p]];  // anchor-positive distance
        for (int k = tid; k < N; k += 256) {
            if (lab[k] != li) {
                const float tm = Drow[k] - dj;           // an - ap
                if (tm > 0.0f && tm <= MARGIN_F) {
                    const float l = MARGIN_F - tm;       // == max(MARGIN-tm, 0)
                    lsum += l;
                    if (l > 0.0f) lcnt++;                // losses > 0 strictly
                }
            }
        }
    }

    // block reduce: wave shuffle then cross-wave LDS
    #pragma unroll
    for (int off = 32; off > 0; off >>= 1) {
        lsum += __shfl_down(lsum, off, 64);
        lcnt += __shfl_down(lcnt, off, 64);
    }
    __shared__ float        sredS[4];
    __shared__ unsigned int sredC[4];
    const int wave = tid >> 6, lane = tid & 63;
    if (lane == 0) { sredS[wave] = lsum; sredC[wave] = lcnt; }
    __syncthreads();
    if (tid == 0) {
        const float        S = sredS[0] + sredS[1] + sredS[2] + sredS[3];
        const unsigned int C = sredC[0] + sredC[1] + sredC[2] + sredC[3];
        if (S != 0.0f || C != 0u) {
            atomicAdd(accum_sum, S);
            atomicAdd(accum_cnt, C);
        }
    }
}

__global__ void finalize_kernel(const float* __restrict__ accum_sum,
                                const unsigned int* __restrict__ accum_cnt,
                                float* __restrict__ out)
{
    const unsigned int c = accum_cnt[0];
    out[0] = (c > 0u) ? (accum_sum[0] / (float)c) : 0.0f;
}

extern "C" void kernel_launch(void* const* d_in, const int* in_sizes, int n_in,
                              void* d_out, int out_size, void* d_ws, size_t ws_size,
                              hipStream_t stream) {
    const float* emb    = (const float*)d_in[0];   // (384, 256) fp32
    const int*   labels = (const int*)d_in[1];     // (384,) int32
    float*       out    = (float*)d_out;           // scalar fp32

    float* ws = (float*)d_ws;
    float* eT  = ws;                       // DIM*N
    float* sq  = eT + (size_t)DIM * N;     // N
    float* Dm  = sq + N;                   // N*N
    float* accum_sum = Dm + (size_t)N * N; // 1 float
    unsigned int* accum_cnt = (unsigned int*)(accum_sum + 1);

    normalize_kernel<<<N, DIM, 0, stream>>>(emb, eT, sq, accum_sum, accum_cnt);
    dist_kernel<<<N, N, 0, stream>>>(eT, sq, Dm);
    triplet_kernel<<<N, 256, 0, stream>>>(Dm, labels, accum_sum, accum_cnt);
    finalize_kernel<<<1, 1, 0, stream>>>(accum_sum, accum_cnt, out);
}

// Round 2
// 78.533 us; speedup vs baseline: 1.0136x; 1.0136x over previous
//
#include <hip/hip_runtime.h>

#define N        384
#define DIM      256
#define MARGIN_F 0.2f
#define NANCH    2              // anchors per fused block
#define NBLK     (N / NANCH)    // 192 fused blocks

// ---------------------------------------------------------------------------
// Workspace layout (floats unless noted):
//   eT    : [0, DIM*N)        normalized embeddings, TRANSPOSED (k-major)
//   sq    : next N            per-row sum(e_norm^2) (~1.0, ref recomputes it)
//   invn  : next N            1/max(norm,1e-12) per row
//   accum : next 1 float (sum), 1 uint (count), 1 uint (blocks-done)
// ---------------------------------------------------------------------------

__global__ __launch_bounds__(DIM) void normalize_kernel(
    const float* __restrict__ emb, float* __restrict__ eT,
    float* __restrict__ sq, float* __restrict__ invn,
    float* __restrict__ accum_sum, unsigned int* __restrict__ accum_cnt,
    unsigned int* __restrict__ done_cnt)
{
    const int row = blockIdx.x;    // 0..N-1
    const int tid = threadIdx.x;   // 0..DIM-1, one element per thread

    float v = emb[row * DIM + tid];
    float s = v * v;
    #pragma unroll
    for (int off = 32; off > 0; off >>= 1) s += __shfl_down(s, off, 64);
    __shared__ float wsum[4];
    const int wave = tid >> 6, lane = tid & 63;
    if (lane == 0) wsum[wave] = s;
    __syncthreads();
    if (tid == 0) wsum[0] = wsum[0] + wsum[1] + wsum[2] + wsum[3];
    __syncthreads();
    const float tot = wsum[0];

    const float inv = 1.0f / fmaxf(sqrtf(tot), 1e-12f);
    eT[tid * N + row] = v * inv;       // transposed: coalesced reads in fused kernel

    if (tid == 0) {
        sq[row]   = tot * inv * inv;   // = sum(e_norm^2), matches ref recompute
        invn[row] = inv;
        if (row == 0) { accum_sum[0] = 0.0f; accum_cnt[0] = 0u; done_cnt[0] = 0u; }
    }
}

__global__ __launch_bounds__(N) void fused_kernel(
    const float* __restrict__ emb, const float* __restrict__ eT,
    const float* __restrict__ sq, const float* __restrict__ invn,
    const int* __restrict__ labels,
    float* __restrict__ accum_sum, unsigned int* __restrict__ accum_cnt,
    unsigned int* __restrict__ done_cnt, float* __restrict__ out)
{
    const int i0  = blockIdx.x * NANCH;       // first anchor of this block
    const int tid = threadIdx.x;              // 0..N-1: one column each

    __shared__ float ei[NANCH][DIM];          // normalized anchor rows
    __shared__ float Drow[NANCH][N];          // distance rows (never hit global)
    __shared__ int   lab[N];
    __shared__ int   posList[NANCH][N];
    __shared__ int   posCnt[NANCH];
    __shared__ float sredS[N / 64];
    __shared__ unsigned int sredC[N / 64];

    // stage normalized anchors (same v*inv expression as normalize_kernel)
    for (int t = tid; t < NANCH * DIM; t += N) {
        const int a = t >> 8, k = t & (DIM - 1);
        ei[a][k] = emb[(i0 + a) * DIM + k] * invn[i0 + a];
    }
    lab[tid] = labels[tid];
    if (tid < NANCH) posCnt[tid] = 0;
    __syncthreads();

    // --- distance rows: thread tid owns column j = tid (coalesced eT reads) ---
    float acc0 = 0.0f, acc1 = 0.0f;
    const float* __restrict__ col = eT + tid;
    #pragma unroll 8
    for (int k = 0; k < DIM; ++k) {
        const float ek = col[k * N];          // coalesced over tid; L2-hot
        acc0 += ei[0][k] * ek;                // LDS broadcast (free)
        acc1 += ei[1][k] * ek;
    }
    const float sqj = sq[tid];
    {
        const float d2 = fmaxf(sq[i0] + sqj - 2.0f * acc0, 0.0f);
        Drow[0][tid] = (d2 > 0.0f) ? sqrtf(d2) : 0.0f;   // ref: sqrt(where(pos,d2,1))*pos
    }
    {
        const float d2 = fmaxf(sq[i0 + 1] + sqj - 2.0f * acc1, 0.0f);
        Drow[1][tid] = (d2 > 0.0f) ? sqrtf(d2) : 0.0f;
    }
    __syncthreads();

    // --- positive lists for both anchors ---
    const int lj = lab[tid];
    #pragma unroll
    for (int a = 0; a < NANCH; ++a) {
        const int ia = i0 + a;
        if (lj == lab[ia] && tid != ia)
            posList[a][atomicAdd(&posCnt[a], 1)] = tid;
    }
    __syncthreads();

    // --- semihard triplet accumulation; thread tid owns negative k = tid ---
    float        lsum = 0.0f;
    unsigned int lcnt = 0u;
    #pragma unroll
    for (int a = 0; a < NANCH; ++a) {
        const int   li = lab[i0 + a];
        const float dk = Drow[a][tid];        // an (if tid is a negative)
        if (lj != li) {
            const int np = posCnt[a];         // ~11 positives
            for (int p = 0; p < np; ++p) {
                const float tm = dk - Drow[a][posList[a][p]];   // an - ap
                if (tm > 0.0f && tm <= MARGIN_F) {
                    const float l = MARGIN_F - tm;              // max(MARGIN-tm,0)
                    lsum += l;
                    if (l > 0.0f) lcnt++;                       // losses > 0 strictly
                }
            }
        }
    }

    // --- block reduce: wave shuffle then cross-wave LDS ---
    #pragma unroll
    for (int off = 32; off > 0; off >>= 1) {
        lsum += __shfl_down(lsum, off, 64);
        lcnt += __shfl_down(lcnt, off, 64);
    }
    const int wave = tid >> 6, lane = tid & 63;
    if (lane == 0) { sredS[wave] = lsum; sredC[wave] = lcnt; }
    __syncthreads();

    if (tid == 0) {
        float        S = 0.0f;
        unsigned int C = 0u;
        #pragma unroll
        for (int w = 0; w < N / 64; ++w) { S += sredS[w]; C += sredC[w]; }
        if (S != 0.0f || C != 0u) {
            atomicAdd(accum_sum, S);
            atomicAdd(accum_cnt, C);
        }
        __threadfence();                       // order accum adds before done++
        const unsigned int prev = atomicAdd(done_cnt, 1);
        if (prev == NBLK - 1) {                // last block finalizes
            const float        Sall = atomicAdd(accum_sum, 0.0f);  // atomic read
            const unsigned int Call = atomicAdd(accum_cnt, 0u);
            out[0] = (Call > 0u) ? (Sall / (float)Call) : 0.0f;
        }
    }
}

extern "C" void kernel_launch(void* const* d_in, const int* in_sizes, int n_in,
                              void* d_out, int out_size, void* d_ws, size_t ws_size,
                              hipStream_t stream) {
    const float* emb    = (const float*)d_in[0];   // (384, 256) fp32
    const int*   labels = (const int*)d_in[1];     // (384,) int32
    float*       out    = (float*)d_out;           // scalar fp32

    float* ws   = (float*)d_ws;
    float* eT   = ws;                        // DIM*N
    float* sq   = eT + (size_t)DIM * N;      // N
    float* invn = sq + N;                    // N
    float* accum_sum = invn + N;             // 1 float
    unsigned int* accum_cnt = (unsigned int*)(accum_sum + 1);
    unsigned int* done_cnt  = accum_cnt + 1;

    normalize_kernel<<<N, DIM, 0, stream>>>(emb, eT, sq, invn,
                                            accum_sum, accum_cnt, done_cnt);
    fused_kernel<<<NBLK, N, 0, stream>>>(emb, eT, sq, invn, labels,
                                         accum_sum, accum_cnt, done_cnt, out);
}